// Round 2
// baseline (720.990 us; speedup 1.0000x reference)
//
#include <hip/hip_runtime.h>
#include <hip/hip_fp16.h>

#define N_NODES 100000
#define EMB_DIM 64
#define N_EDGES 3200000
#define N_LAYERS 3

#define SCAN_BLOCK 512
#define N_SCAN_BLOCKS ((N_NODES + SCAN_BLOCK - 1) / SCAN_BLOCK)   // 196

// d_out layout: mean [N_NODES*64] first, then stacked [N_NODES*4*64]
// stacked[n][l][d] at n*256 + l*64 + d

__device__ __forceinline__ unsigned short f32_to_bf16_rtn(float f) {
    unsigned u = __float_as_uint(f);
    unsigned r = u + 0x7FFFu + ((u >> 16) & 1u);
    return (unsigned short)(r >> 16);
}
__device__ __forceinline__ float bf16_to_f32(unsigned short h) {
    return __uint_as_float(((unsigned)h) << 16);
}

// ---------- CSR build ----------

__global__ void count_rows(const int* __restrict__ rows, int* __restrict__ counts) {
    int e = blockIdx.x * blockDim.x + threadIdx.x;
    if (e >= N_EDGES) return;
    atomicAdd(&counts[rows[e]], 1);
}

__global__ void __launch_bounds__(SCAN_BLOCK) scan_phase1(const int* __restrict__ counts,
                                                          int* __restrict__ blockSums) {
    __shared__ int sm[SCAN_BLOCK];
    int idx = blockIdx.x * SCAN_BLOCK + threadIdx.x;
    int v = (idx < N_NODES) ? counts[idx] : 0;
    sm[threadIdx.x] = v;
    __syncthreads();
    for (int off = SCAN_BLOCK / 2; off > 0; off >>= 1) {
        if (threadIdx.x < off) sm[threadIdx.x] += sm[threadIdx.x + off];
        __syncthreads();
    }
    if (threadIdx.x == 0) blockSums[blockIdx.x] = sm[0];
}

__global__ void __launch_bounds__(256) scan_phase2(const int* __restrict__ blockSums,
                                                   int* __restrict__ blockOffs,
                                                   int* __restrict__ row_ptr) {
    __shared__ int sm[256];
    int t = threadIdx.x;
    int v = (t < N_SCAN_BLOCKS) ? blockSums[t] : 0;
    sm[t] = v;
    __syncthreads();
    for (int off = 1; off < 256; off <<= 1) {
        int u = (t >= off) ? sm[t - off] : 0;
        __syncthreads();
        sm[t] += u;
        __syncthreads();
    }
    if (t < N_SCAN_BLOCKS) blockOffs[t] = (t == 0) ? 0 : sm[t - 1];
    if (t == 255) row_ptr[N_NODES] = sm[255];
}

__global__ void __launch_bounds__(SCAN_BLOCK) scan_phase3(const int* __restrict__ counts,
                                                          const int* __restrict__ blockOffs,
                                                          int* __restrict__ row_ptr) {
    __shared__ int sm[SCAN_BLOCK];
    int idx = blockIdx.x * SCAN_BLOCK + threadIdx.x;
    int t = threadIdx.x;
    int v = (idx < N_NODES) ? counts[idx] : 0;
    sm[t] = v;
    __syncthreads();
    for (int off = 1; off < SCAN_BLOCK; off <<= 1) {
        int u = (t >= off) ? sm[t - off] : 0;
        __syncthreads();
        sm[t] += u;
        __syncthreads();
    }
    if (idx < N_NODES) row_ptr[idx] = blockOffs[blockIdx.x] + sm[t] - v;
}

// Packed edge: col (17 bits) << 15 | fp16(val) low 15 bits (val>=0 so sign=0).
__global__ void scatter_edges_packed(const int* __restrict__ rows, const int* __restrict__ cols,
                                     const float* __restrict__ vals,
                                     const int* __restrict__ row_ptr, int* __restrict__ fill,
                                     unsigned* __restrict__ s_edges) {
    int e = blockIdx.x * blockDim.x + threadIdx.x;
    if (e >= N_EDGES) return;
    int r = rows[e];
    int pos = row_ptr[r] + atomicAdd(&fill[r], 1);
    unsigned hb = __half_as_ushort(__float2half(vals[e]));
    s_edges[pos] = (((unsigned)cols[e]) << 15) | (hb & 0x7FFFu);
}

// ---------- emb -> bf16 mirror ----------
__global__ void emb_to_bf16(const float* __restrict__ emb, ushort4* __restrict__ mirror) {
    int t = blockIdx.x * blockDim.x + threadIdx.x;   // [0, N_NODES*16)
    if (t >= N_NODES * 16) return;
    float4 v = ((const float4*)emb)[t];
    ushort4 o;
    o.x = f32_to_bf16_rtn(v.x); o.y = f32_to_bf16_rtn(v.y);
    o.z = f32_to_bf16_rtn(v.z); o.w = f32_to_bf16_rtn(v.w);
    mirror[t] = o;
}

// ---------- SpMM gather core, bf16 source: one wave per destination node ----------
// 4 groups x 16 lanes; lane j of a group owns bf16x4 chunk j of the 64-dim row.
// Edge words staged via ONE coalesced per-lane load, distributed with __shfl.
// CONTROL FLOW IS WAVE-UNIFORM: nfull is uniform across the wave, the chunk
// loop condition (kb < nfull) is uniform, and all shfls execute with all 64
// lanes active (shfl from an inactive lane is undefined on CDNA — R1 bug).

__device__ __forceinline__ void gacc(float4& acc, unsigned p, int j,
                                     const unsigned short* __restrict__ srcMirror) {
    float v = __half2float(__ushort_as_half((unsigned short)(p & 0x7FFFu)));
    ushort4 m = *(const ushort4*)(srcMirror + (size_t)(p >> 15) * 64 + j * 4);
    acc.x += v * bf16_to_f32(m.x);
    acc.y += v * bf16_to_f32(m.y);
    acc.z += v * bf16_to_f32(m.z);
    acc.w += v * bf16_to_f32(m.w);
}

__device__ __forceinline__ float4 spmm_row_core(int beg, int end, int g, int j, int lane,
                                                const unsigned* __restrict__ s_edges,
                                                const unsigned short* __restrict__ srcMirror) {
    int deg = end - beg;                  // wave-uniform
    // One coalesced load stages up to 64 edge words for this row across the wave.
    // Lanes >= deg hold 0 (col 0, val +0.0) so they contribute nothing if used.
    unsigned ew = (lane < deg) ? s_edges[beg + lane] : 0u;
    float4 acc = make_float4(0.f, 0.f, 0.f, 0.f);
    int nfull = deg < 64 ? deg : 64;      // wave-uniform
    // Uniform chunk loop: all 64 lanes enter/exit together.
    for (int kb = 0; kb < nfull; kb += 16) {
        int k0 = kb + g, k1 = kb + g + 4, k2 = kb + g + 8, k3 = kb + g + 12;
        // shfls unconditional: every source lane is active. k <= 63 always.
        unsigned p0 = __shfl(ew, k0);
        unsigned p1 = __shfl(ew, k1);
        unsigned p2 = __shfl(ew, k2);
        unsigned p3 = __shfl(ew, k3);
        // Guards are group-uniform; they only skip wasted tail gathers.
        if (k0 < nfull) gacc(acc, p0, j, srcMirror);
        if (k1 < nfull) gacc(acc, p1, j, srcMirror);
        if (k2 < nfull) gacc(acc, p2, j, srcMirror);
        if (k3 < nfull) gacc(acc, p3, j, srcMirror);
    }
    // Rare tail: rows with degree > 64 (Poisson(32): ~4e-6 of nodes).
    // Direct loads, no cross-lane ops -> divergence here is harmless.
    for (int e = beg + 64 + g; e < end; e += 4) {
        unsigned p = s_edges[e];
        gacc(acc, p, j, srcMirror);
    }
    // Reduce the 4 groups (wave fully reconverged here).
    acc.x += __shfl_xor(acc.x, 16); acc.y += __shfl_xor(acc.y, 16);
    acc.z += __shfl_xor(acc.z, 16); acc.w += __shfl_xor(acc.w, 16);
    acc.x += __shfl_xor(acc.x, 32); acc.y += __shfl_xor(acc.y, 32);
    acc.z += __shfl_xor(acc.z, 32); acc.w += __shfl_xor(acc.w, 32);
    return acc;
}

__global__ void __launch_bounds__(256) spmm_gather_bf16_mid(const int* __restrict__ row_ptr,
                                                            const unsigned* __restrict__ s_edges,
                                                            const unsigned short* __restrict__ srcMirror,
                                                            float* __restrict__ dstStacked,
                                                            unsigned short* __restrict__ dstMirror) {
    int wave = (blockIdx.x * blockDim.x + threadIdx.x) >> 6;
    if (wave >= N_NODES) return;
    int lane = threadIdx.x & 63;
    int g = lane >> 4, j = lane & 15;
    float4 acc = spmm_row_core(row_ptr[wave], row_ptr[wave + 1], g, j, lane, s_edges, srcMirror);
    if (lane < 16) {
        *(float4*)(dstStacked + (size_t)wave * 256 + j * 4) = acc;
        ushort4 o;
        o.x = f32_to_bf16_rtn(acc.x); o.y = f32_to_bf16_rtn(acc.y);
        o.z = f32_to_bf16_rtn(acc.z); o.w = f32_to_bf16_rtn(acc.w);
        *(ushort4*)(dstMirror + (size_t)wave * 64 + j * 4) = o;
    }
}

// Last layer: fuse the 4-layer mean + layer-0 copy into the same dispatch.
__global__ void __launch_bounds__(256) spmm_gather_bf16_last(const int* __restrict__ row_ptr,
                                                             const unsigned* __restrict__ s_edges,
                                                             const unsigned short* __restrict__ srcMirror,
                                                             const float* __restrict__ emb,
                                                             float* __restrict__ stacked,
                                                             float* __restrict__ meanOut) {
    int wave = (blockIdx.x * blockDim.x + threadIdx.x) >> 6;
    if (wave >= N_NODES) return;
    int lane = threadIdx.x & 63;
    int g = lane >> 4, j = lane & 15;
    float4 acc = spmm_row_core(row_ptr[wave], row_ptr[wave + 1], g, j, lane, s_edges, srcMirror);
    if (lane < 16) {
        float4* base = (float4*)stacked + (size_t)wave * 64;
        float4 a = ((const float4*)emb)[wave * 16 + j];
        float4 b = base[16 + j];
        float4 c = base[32 + j];
        base[j] = a;          // layer 0
        base[48 + j] = acc;   // layer 3
        float4 s;
        s.x = 0.25f * (a.x + b.x + c.x + acc.x);
        s.y = 0.25f * (a.y + b.y + c.y + acc.y);
        s.z = 0.25f * (a.z + b.z + c.z + acc.z);
        s.w = 0.25f * (a.w + b.w + c.w + acc.w);
        ((float4*)meanOut)[wave * 16 + j] = s;
    }
}

// ---------- mean over 4 layers (f32 fallback path) ----------
__global__ void mean_layers(const float* __restrict__ emb,
                            float* __restrict__ stacked,
                            float* __restrict__ meanOut) {
    int t = blockIdx.x * blockDim.x + threadIdx.x;   // [0, N_NODES*16)
    if (t >= N_NODES * 16) return;
    int n = t >> 4;
    int j = t & 15;
    float4* base = (float4*)stacked + (size_t)n * 64;
    float4 a = ((const float4*)emb)[t];
    float4 b = base[16 + j];
    float4 c = base[32 + j];
    float4 d = base[48 + j];
    base[j] = a;
    float4 s;
    s.x = 0.25f * (a.x + b.x + c.x + d.x);
    s.y = 0.25f * (a.y + b.y + c.y + d.y);
    s.z = 0.25f * (a.z + b.z + c.z + d.z);
    s.w = 0.25f * (a.w + b.w + c.w + d.w);
    ((float4*)meanOut)[t] = s;
}

// ---------- mid fallback: fp32 CSR gather ----------

__global__ void scatter_edges_int2(const int* __restrict__ rows, const int* __restrict__ cols,
                                   const float* __restrict__ vals,
                                   const int* __restrict__ row_ptr, int* __restrict__ fill,
                                   int2* __restrict__ s_colval) {
    int e = blockIdx.x * blockDim.x + threadIdx.x;
    if (e >= N_EDGES) return;
    int r = rows[e];
    int pos = row_ptr[r] + atomicAdd(&fill[r], 1);
    int2 p; p.x = cols[e]; p.y = __float_as_int(vals[e]);
    s_colval[pos] = p;
}

__global__ void __launch_bounds__(256) spmm_gather_f32(const int* __restrict__ row_ptr,
                                                       const int2* __restrict__ s_colval,
                                                       const float* __restrict__ src, int srcStride,
                                                       float* __restrict__ dst) {
    int wave = (blockIdx.x * blockDim.x + threadIdx.x) >> 6;
    if (wave >= N_NODES) return;
    int lane = threadIdx.x & 63;
    int g = lane >> 4, j = lane & 15;
    int beg = row_ptr[wave], end = row_ptr[wave + 1];
    float4 acc = make_float4(0.f, 0.f, 0.f, 0.f);
    int e = beg + g;
    for (; e + 4 < end; e += 8) {
        int2 p0 = s_colval[e], p1 = s_colval[e + 4];
        float v0 = __int_as_float(p0.y), v1 = __int_as_float(p1.y);
        float4 m0 = *(const float4*)(src + (size_t)p0.x * srcStride + j * 4);
        float4 m1 = *(const float4*)(src + (size_t)p1.x * srcStride + j * 4);
        acc.x += v0 * m0.x + v1 * m1.x; acc.y += v0 * m0.y + v1 * m1.y;
        acc.z += v0 * m0.z + v1 * m1.z; acc.w += v0 * m0.w + v1 * m1.w;
    }
    for (; e < end; e += 4) {
        int2 p = s_colval[e];
        float v = __int_as_float(p.y);
        float4 m = *(const float4*)(src + (size_t)p.x * srcStride + j * 4);
        acc.x += v * m.x; acc.y += v * m.y; acc.z += v * m.z; acc.w += v * m.w;
    }
    acc.x += __shfl_xor(acc.x, 16); acc.y += __shfl_xor(acc.y, 16);
    acc.z += __shfl_xor(acc.z, 16); acc.w += __shfl_xor(acc.w, 16);
    acc.x += __shfl_xor(acc.x, 32); acc.y += __shfl_xor(acc.y, 32);
    acc.z += __shfl_xor(acc.z, 32); acc.w += __shfl_xor(acc.w, 32);
    if (lane < 16)
        *(float4*)(dst + (size_t)wave * 256 + j * 4) = acc;
}

// ---------- last fallback: atomic scatter ----------

__global__ void init_stacked_full(const float* __restrict__ emb, float* __restrict__ stacked) {
    int t = blockIdx.x * blockDim.x + threadIdx.x;
    if (t >= N_NODES * 64) return;
    int n = t >> 6, j = t & 63;
    float4 v = (j < 16) ? ((const float4*)emb)[n * 16 + j] : make_float4(0.f, 0.f, 0.f, 0.f);
    ((float4*)stacked)[n * 64 + j] = v;
}

__global__ void spmm_atomic(const int* __restrict__ rows, const int* __restrict__ cols,
                            const float* __restrict__ vals, float* __restrict__ stacked,
                            int lprev) {
    int t = blockIdx.x * blockDim.x + threadIdx.x;
    int e = t >> 4, j = t & 15;
    if (e >= N_EDGES) return;
    int r = rows[e], c = cols[e];
    float v = vals[e];
    const float4* src = (const float4*)(stacked + (size_t)c * 256 + lprev * 64);
    float4 m = src[j];
    float* dst = stacked + (size_t)r * 256 + (lprev + 1) * 64 + j * 4;
    atomicAdd(dst + 0, v * m.x); atomicAdd(dst + 1, v * m.y);
    atomicAdd(dst + 2, v * m.z); atomicAdd(dst + 3, v * m.w);
}

__global__ void mean_layers_plain(const float* __restrict__ stacked, float* __restrict__ meanOut) {
    int t = blockIdx.x * blockDim.x + threadIdx.x;
    if (t >= N_NODES * 16) return;
    int n = t >> 4, j = t & 15;
    const float4* base = (const float4*)(stacked + (size_t)n * 256);
    float4 a = base[j], b = base[16 + j], c = base[32 + j], d = base[48 + j];
    float4 s;
    s.x = 0.25f * (a.x + b.x + c.x + d.x);
    s.y = 0.25f * (a.y + b.y + c.y + d.y);
    s.z = 0.25f * (a.z + b.z + c.z + d.z);
    s.w = 0.25f * (a.w + b.w + c.w + d.w);
    ((float4*)meanOut)[t] = s;
}

extern "C" void kernel_launch(void* const* d_in, const int* in_sizes, int n_in,
                              void* d_out, int out_size, void* d_ws, size_t ws_size,
                              hipStream_t stream) {
    const float* emb  = (const float*)d_in[0];
    const int*   rows = (const int*)d_in[1];
    const int*   cols = (const int*)d_in[2];
    const float* vals = (const float*)d_in[3];

    float* meanOut = (float*)d_out;
    float* stacked = (float*)d_out + (size_t)N_NODES * EMB_DIM;

    const size_t headInts = (size_t)(N_NODES * 2 + 1 + 2 * N_SCAN_BLOCKS);
    size_t need_bf16 = headInts * sizeof(int) + 64
                     + (size_t)N_EDGES * sizeof(unsigned)
                     + 2 * (size_t)N_NODES * EMB_DIM * sizeof(unsigned short);
    size_t need_f32  = headInts * sizeof(int) + 64 + (size_t)N_EDGES * sizeof(int2);

    if (ws_size >= need_bf16) {
        char* w = (char*)d_ws;
        int* counts    = (int*)w;  w += (size_t)N_NODES * sizeof(int);
        int* row_ptr   = (int*)w;  w += (size_t)(N_NODES + 1) * sizeof(int);
        int* blockSums = (int*)w;  w += (size_t)N_SCAN_BLOCKS * sizeof(int);
        int* blockOffs = (int*)w;  w += (size_t)N_SCAN_BLOCKS * sizeof(int);
        w = (char*)(((uintptr_t)w + 15) & ~(uintptr_t)15);
        unsigned* s_edges = (unsigned*)w;  w += (size_t)N_EDGES * sizeof(unsigned);
        unsigned short* mirrorA = (unsigned short*)w;  w += (size_t)N_NODES * EMB_DIM * sizeof(unsigned short);
        unsigned short* mirrorB = (unsigned short*)w;

        hipMemsetAsync(counts, 0, (size_t)N_NODES * sizeof(int), stream);
        {
            int block = 256, grid = (N_EDGES + block - 1) / block;
            count_rows<<<grid, block, 0, stream>>>(rows, counts);
        }
        scan_phase1<<<N_SCAN_BLOCKS, SCAN_BLOCK, 0, stream>>>(counts, blockSums);
        scan_phase2<<<1, 256, 0, stream>>>(blockSums, blockOffs, row_ptr);
        scan_phase3<<<N_SCAN_BLOCKS, SCAN_BLOCK, 0, stream>>>(counts, blockOffs, row_ptr);
        hipMemsetAsync(counts, 0, (size_t)N_NODES * sizeof(int), stream);
        {
            int block = 256, grid = (N_EDGES + block - 1) / block;
            scatter_edges_packed<<<grid, block, 0, stream>>>(rows, cols, vals, row_ptr, counts, s_edges);
        }
        {
            int total = N_NODES * 16;
            int block = 256, grid = (total + block - 1) / block;
            emb_to_bf16<<<grid, block, 0, stream>>>(emb, (ushort4*)mirrorA);
        }
        {
            long long threads = (long long)N_NODES * 64;
            int block = 256;
            int grid = (int)((threads + block - 1) / block);
            spmm_gather_bf16_mid<<<grid, block, 0, stream>>>(row_ptr, s_edges, mirrorA, stacked + 1 * 64, mirrorB);
            spmm_gather_bf16_mid<<<grid, block, 0, stream>>>(row_ptr, s_edges, mirrorB, stacked + 2 * 64, mirrorA);
            spmm_gather_bf16_last<<<grid, block, 0, stream>>>(row_ptr, s_edges, mirrorA, emb, stacked, meanOut);
        }
    } else if (ws_size >= need_f32) {
        char* w = (char*)d_ws;
        int* counts    = (int*)w;  w += (size_t)N_NODES * sizeof(int);
        int* row_ptr   = (int*)w;  w += (size_t)(N_NODES + 1) * sizeof(int);
        int* blockSums = (int*)w;  w += (size_t)N_SCAN_BLOCKS * sizeof(int);
        int* blockOffs = (int*)w;  w += (size_t)N_SCAN_BLOCKS * sizeof(int);
        w = (char*)(((uintptr_t)w + 15) & ~(uintptr_t)15);
        int2* s_colval = (int2*)w;

        hipMemsetAsync(counts, 0, (size_t)N_NODES * sizeof(int), stream);
        {
            int block = 256, grid = (N_EDGES + block - 1) / block;
            count_rows<<<grid, block, 0, stream>>>(rows, counts);
        }
        scan_phase1<<<N_SCAN_BLOCKS, SCAN_BLOCK, 0, stream>>>(counts, blockSums);
        scan_phase2<<<1, 256, 0, stream>>>(blockSums, blockOffs, row_ptr);
        scan_phase3<<<N_SCAN_BLOCKS, SCAN_BLOCK, 0, stream>>>(counts, blockOffs, row_ptr);
        hipMemsetAsync(counts, 0, (size_t)N_NODES * sizeof(int), stream);
        {
            int block = 256, grid = (N_EDGES + block - 1) / block;
            scatter_edges_int2<<<grid, block, 0, stream>>>(rows, cols, vals, row_ptr, counts, s_colval);
        }
        {
            long long threads = (long long)N_NODES * 64;
            int block = 256;
            int grid = (int)((threads + block - 1) / block);
            spmm_gather_f32<<<grid, block, 0, stream>>>(row_ptr, s_colval, emb, 64, stacked + 1 * 64);
            spmm_gather_f32<<<grid, block, 0, stream>>>(row_ptr, s_colval, stacked + 1 * 64, 256, stacked + 2 * 64);
            spmm_gather_f32<<<grid, block, 0, stream>>>(row_ptr, s_colval, stacked + 2 * 64, 256, stacked + 3 * 64);
        }
        {
            int total = N_NODES * 16;
            int block = 256, grid = (total + block - 1) / block;
            mean_layers<<<grid, block, 0, stream>>>(emb, stacked, meanOut);
        }
    } else {
        {
            int total = N_NODES * 64;
            int block = 256, grid = (total + block - 1) / block;
            init_stacked_full<<<grid, block, 0, stream>>>(emb, stacked);
        }
        {
            long long total = (long long)N_EDGES * 16;
            int block = 256, grid = (int)((total + block - 1) / block);
            for (int l = 0; l < N_LAYERS; ++l)
                spmm_atomic<<<grid, block, 0, stream>>>(rows, cols, vals, stacked, l);
        }
        {
            int total = N_NODES * 16;
            int block = 256, grid = (total + block - 1) / block;
            mean_layers_plain<<<grid, block, 0, stream>>>(stacked, meanOut);
        }
    }
}